// Round 1
// baseline (175.557 us; speedup 1.0000x reference)
//
#include <hip/hip_runtime.h>
#include <hip/hip_bf16.h>

#define IN_F 256
#define OUT_F 4096
#define BATCH 8192

// Kernel 1: recover the one-hot source index per output feature.
// One 64-lane wave per row of expansion_mapping [OUT_F, IN_F].
// Fully coalesced: lane L reads em[row*IN_F + c + L].
__global__ __launch_bounds__(256) void urbf_build_idx(
    const float* __restrict__ em, int* __restrict__ idx) {
    const int wave = blockIdx.x * (blockDim.x >> 6) + (threadIdx.x >> 6);
    const int lane = threadIdx.x & 63;
    if (wave >= OUT_F) return;
    const float* row = em + (size_t)wave * IN_F;
    int found = 0;
    #pragma unroll
    for (int c = 0; c < IN_F; c += 64) {
        const float v = row[c + lane];
        const unsigned long long m = __ballot(v != 0.0f);
        if (m) found = c + (int)(__ffsll((unsigned long long)m) - 1);
    }
    if (lane == 0) idx[wave] = found;
}

// Kernel 2: out[b,j] = exp(-0.5*((x[b,idx[j]]-means[j])/vars[j])^2)*coefs[j]
// One float4 (4 consecutive j) per thread -> 16B/lane coalesced stores.
__global__ __launch_bounds__(256) void urbf_main(
    const float* __restrict__ x, const int* __restrict__ idx,
    const float* __restrict__ means, const float* __restrict__ vars_,
    const float* __restrict__ coefs, float* __restrict__ out) {
    const int g = blockIdx.x * blockDim.x + threadIdx.x;   // float4 index
    const int b  = g >> 10;            // OUT_F/4 = 1024 float4 per row
    const int j4 = g & 1023;
    const int j  = j4 << 2;

    const int4   si = *(const int4*)(idx + j);
    const float4 mu = *(const float4*)(means + j);
    const float4 vv = *(const float4*)(vars_ + j);
    const float4 cc = *(const float4*)(coefs + j);

    const float* xrow = x + (size_t)b * IN_F;   // 1 KiB row, L1-resident
    const float x0 = xrow[si.x];
    const float x1 = xrow[si.y];
    const float x2 = xrow[si.z];
    const float x3 = xrow[si.w];

    float4 o;
    float z;
    z = (x0 - mu.x) / vv.x; o.x = __expf(-0.5f * z * z) * cc.x;
    z = (x1 - mu.y) / vv.y; o.y = __expf(-0.5f * z * z) * cc.y;
    z = (x2 - mu.z) / vv.z; o.z = __expf(-0.5f * z * z) * cc.z;
    z = (x3 - mu.w) / vv.w; o.w = __expf(-0.5f * z * z) * cc.w;

    *(float4*)(out + ((size_t)g << 2)) = o;
}

extern "C" void kernel_launch(void* const* d_in, const int* in_sizes, int n_in,
                              void* d_out, int out_size, void* d_ws, size_t ws_size,
                              hipStream_t stream) {
    const float* x     = (const float*)d_in[0];   // [BATCH, IN_F]
    const float* em    = (const float*)d_in[1];   // [OUT_F, IN_F]
    const float* means = (const float*)d_in[2];   // [OUT_F]
    const float* vars_ = (const float*)d_in[3];   // [OUT_F]
    const float* coefs = (const float*)d_in[4];   // [OUT_F]
    float* out = (float*)d_out;                   // [BATCH, OUT_F]
    int* idx = (int*)d_ws;                        // 4096 ints = 16 KiB

    // Kernel 1: 4096 waves, 4 waves/block -> 1024 blocks.
    urbf_build_idx<<<OUT_F / 4, 256, 0, stream>>>(em, idx);

    // Kernel 2: BATCH*OUT_F/4 float4 elements, 256 threads/block.
    const int total4 = BATCH * OUT_F / 4;         // 8,388,608
    urbf_main<<<total4 / 256, 256, 0, stream>>>(x, idx, means, vars_, coefs, out);
}

// Round 3
// 162.826 us; speedup vs baseline: 1.0782x; 1.0782x over previous
//
#include <hip/hip_runtime.h>
#include <hip/hip_bf16.h>

#define IN_F 256
#define OUT_F 4096
#define BATCH 8192
#define B_PER_BLOCK 16   // batch rows per block; grid.y = 512 -> 2048 blocks

typedef float v4f __attribute__((ext_vector_type(4)));  // native vec for nontemporal store

// Kernel 1: recover the one-hot source index per output feature.
// One 64-lane wave per row of expansion_mapping [OUT_F, IN_F].
__global__ __launch_bounds__(256) void urbf_build_idx(
    const float* __restrict__ em, int* __restrict__ idx) {
    const int wave = blockIdx.x * (blockDim.x >> 6) + (threadIdx.x >> 6);
    const int lane = threadIdx.x & 63;
    if (wave >= OUT_F) return;
    const float* row = em + (size_t)wave * IN_F;
    int found = 0;
    #pragma unroll
    for (int c = 0; c < IN_F; c += 64) {
        const float v = row[c + lane];
        const unsigned long long m = __ballot(v != 0.0f);
        if (m) found = c + (int)(__ffsll((unsigned long long)m) - 1);
    }
    if (lane == 0) idx[wave] = found;
}

// Kernel 2: each thread owns 4 consecutive output features (one float4 of j),
// loads its params ONCE into registers, then streams over B_PER_BLOCK batch
// rows. out[b,j] = exp2(a*(x[b,si]-mu)^2)*cc with a = -0.5*log2(e)/vars^2.
__global__ __launch_bounds__(256) void urbf_main(
    const float* __restrict__ x, const int* __restrict__ idx,
    const float* __restrict__ means, const float* __restrict__ vars_,
    const float* __restrict__ coefs, float* __restrict__ out) {
    const int j4 = blockIdx.x * 256 + threadIdx.x;   // blockIdx.x in [0,4)
    const int j  = j4 << 2;

    const int4   si = *(const int4*)(idx + j);
    const float4 mu = *(const float4*)(means + j);
    const float4 vv = *(const float4*)(vars_ + j);
    const float4 cc = *(const float4*)(coefs + j);

    // a = -0.5*log2(e) / v^2  (fold the division + exp base-change into one mul)
    const float C = -0.72134752044448170368f;  // -0.5 * log2(e)
    float4 a;
    {
        float4 r;
        r.x = __frcp_rn(vv.x); r.y = __frcp_rn(vv.y);
        r.z = __frcp_rn(vv.z); r.w = __frcp_rn(vv.w);
        a.x = C * r.x * r.x; a.y = C * r.y * r.y;
        a.z = C * r.z * r.z; a.w = C * r.w * r.w;
    }

    const int b0 = blockIdx.y * B_PER_BLOCK;
    #pragma unroll 4
    for (int bb = 0; bb < B_PER_BLOCK; ++bb) {
        const int b = b0 + bb;
        const float* xrow = x + (size_t)b * IN_F;  // 1 KiB row, L1-resident
        const float x0 = xrow[si.x];
        const float x1 = xrow[si.y];
        const float x2 = xrow[si.z];
        const float x3 = xrow[si.w];

        v4f o; float d;
        d = x0 - mu.x; o.x = exp2f(d * d * a.x) * cc.x;
        d = x1 - mu.y; o.y = exp2f(d * d * a.y) * cc.y;
        d = x2 - mu.z; o.z = exp2f(d * d * a.z) * cc.z;
        d = x3 - mu.w; o.w = exp2f(d * d * a.w) * cc.w;

        __builtin_nontemporal_store(o, (v4f*)(out + (size_t)b * OUT_F + j));
    }
}

extern "C" void kernel_launch(void* const* d_in, const int* in_sizes, int n_in,
                              void* d_out, int out_size, void* d_ws, size_t ws_size,
                              hipStream_t stream) {
    const float* x     = (const float*)d_in[0];   // [BATCH, IN_F]
    const float* em    = (const float*)d_in[1];   // [OUT_F, IN_F]
    const float* means = (const float*)d_in[2];   // [OUT_F]
    const float* vars_ = (const float*)d_in[3];   // [OUT_F]
    const float* coefs = (const float*)d_in[4];   // [OUT_F]
    float* out = (float*)d_out;                   // [BATCH, OUT_F]
    int* idx = (int*)d_ws;                        // 4096 ints = 16 KiB

    // Kernel 1: 4096 waves, 4 waves/block -> 1024 blocks.
    urbf_build_idx<<<OUT_F / 4, 256, 0, stream>>>(em, idx);

    // Kernel 2: grid (j-chunks=4, b-chunks=512), 256 threads.
    dim3 grid(OUT_F / 4 / 256, BATCH / B_PER_BLOCK);
    urbf_main<<<grid, 256, 0, stream>>>(x, idx, means, vars_, coefs, out);
}